// Round 9
// baseline (338.347 us; speedup 1.0000x reference)
//
#include <hip/hip_runtime.h>
#include <hip/hip_bf16.h>
#include <math.h>

#define NHEADS 2

typedef unsigned short u16;
typedef __attribute__((ext_vector_type(8))) unsigned short u16x8;
typedef __attribute__((ext_vector_type(4))) unsigned short u16x4;
typedef __attribute__((ext_vector_type(8))) short short8;
typedef __attribute__((ext_vector_type(4))) short short4v;
typedef __attribute__((ext_vector_type(4))) float f32x4;

__device__ __forceinline__ u16 f2bf(float x) {
    __hip_bfloat16 h = __float2bfloat16(x);
    return __builtin_bit_cast(unsigned short, h);
}

// ---------------------------------------------------------------------------
// Transpose + bf16 convert: f [b, c, l] fp32  ->  ft [b, l, c] bf16.
// ---------------------------------------------------------------------------
__global__ __launch_bounds__(256) void transpose_bf16_kernel(
    const float* __restrict__ s0, const float* __restrict__ s1,
    const float* __restrict__ s2,
    u16* __restrict__ d0, u16* __restrict__ d1, u16* __restrict__ d2,
    int C, int L)
{
    const int z = blockIdx.z;
    const int which = z >> 1;
    const int b = z & 1;
    const float* __restrict__ src = (which == 0) ? s0 : (which == 1 ? s1 : s2);
    u16* __restrict__ dst = (which == 0) ? d0 : (which == 1 ? d1 : d2);
    const int l0 = blockIdx.x * 32;
    const int c0 = blockIdx.y * 32;
    __shared__ float Ts[32][33];
    const int t = threadIdx.x;
    const int x = t & 31, y = t >> 5;
    #pragma unroll
    for (int p = 0; p < 4; ++p)
        Ts[y + 8 * p][x] = src[((size_t)(b * C + c0 + y + 8 * p)) * L + l0 + x];
    __syncthreads();
    #pragma unroll
    for (int p = 0; p < 4; ++p)
        dst[((size_t)(b * L + l0 + y + 8 * p)) * C + c0 + x] = f2bf(Ts[x][y + 8 * p]);
}

// ---------------------------------------------------------------------------
// Fused qkv GEMM, both attentions in one launch.
// ---------------------------------------------------------------------------
__global__ __launch_bounds__(256) void gemm_qkv(
    const u16* __restrict__ f1t, const u16* __restrict__ f2t,
    const u16* __restrict__ f3t,
    const float* __restrict__ w12, const float* __restrict__ b12,
    const float* __restrict__ w13, const float* __restrict__ b13,
    u16* __restrict__ Qa, u16* __restrict__ Ka, u16* __restrict__ Va,
    u16* __restrict__ Qb, u16* __restrict__ Kb, u16* __restrict__ Vb,
    int M, int C, int L, int dh, float qscale, int gx, int perAtt)
{
    const int att = blockIdx.x / perAtt;
    const int r = blockIdx.x - att * perAtt;
    const int n0 = (r % gx) * 64;
    const int m0 = (r / gx) * 64;
    const int K = C;
    __shared__ __align__(16) u16 Xs[64][72];
    __shared__ __align__(16) u16 Ws[64][72];
    const int tid = threadIdx.x;
    const int wid = tid >> 6, lane = tid & 63;
    const int lo = lane & 15, hi = lane >> 4;
    const int wm = wid >> 1, wn = wid & 1;

    const u16* __restrict__ X = (n0 < C) ? f1t : (att ? f3t : f2t);
    const float* __restrict__ W = att ? w13 : w12;
    const float* __restrict__ bias = att ? b13 : b12;

    f32x4 acc[2][2];
    #pragma unroll
    for (int i = 0; i < 2; ++i)
        #pragma unroll
        for (int j = 0; j < 2; ++j)
            #pragma unroll
            for (int rr = 0; rr < 4; ++rr) acc[i][j][rr] = 0.f;

    u16x8 xreg[2];
    f32x4 wreg[4];

    auto load_x = [&](int k0) {
        #pragma unroll
        for (int p = 0; p < 2; ++p) {
            int c = tid + p * 256;
            int row = c >> 3, kc = c & 7;
            xreg[p] = *(const u16x8*)&X[(size_t)(m0 + row) * K + k0 + kc * 8];
        }
    };
    auto load_w = [&](int k0) {
        #pragma unroll
        for (int p = 0; p < 4; ++p) {
            int c = tid + p * 256;
            int row = c >> 4, kc = c & 15;
            wreg[p] = *(const f32x4*)&W[(size_t)(n0 + row) * K + k0 + kc * 4];
        }
    };

    load_x(0);
    load_w(0);
    const int ns = K / 64;
    for (int s = 0; s < ns; ++s) {
        __syncthreads();
        #pragma unroll
        for (int p = 0; p < 2; ++p) {
            int c = tid + p * 256;
            int row = c >> 3, kc = c & 7;
            *(u16x8*)&Xs[row][kc * 8] = xreg[p];
        }
        #pragma unroll
        for (int p = 0; p < 4; ++p) {
            int c = tid + p * 256;
            int row = c >> 4, kc = c & 15;
            u16x4 cv = {f2bf(wreg[p][0]), f2bf(wreg[p][1]),
                        f2bf(wreg[p][2]), f2bf(wreg[p][3])};
            *(u16x4*)&Ws[row][kc * 4] = cv;
        }
        __syncthreads();
        if (s + 1 < ns) { load_x((s + 1) * 64); load_w((s + 1) * 64); }
        #pragma unroll
        for (int kk = 0; kk < 2; ++kk) {
            short8 wf0 = *(const short8*)&Ws[wn * 32 + lo][kk * 32 + hi * 8];
            short8 wf1 = *(const short8*)&Ws[wn * 32 + 16 + lo][kk * 32 + hi * 8];
            short8 xf0 = *(const short8*)&Xs[wm * 32 + lo][kk * 32 + hi * 8];
            short8 xf1 = *(const short8*)&Xs[wm * 32 + 16 + lo][kk * 32 + hi * 8];
            acc[0][0] = __builtin_amdgcn_mfma_f32_16x16x32_bf16(wf0, xf0, acc[0][0], 0, 0, 0);
            acc[0][1] = __builtin_amdgcn_mfma_f32_16x16x32_bf16(wf1, xf0, acc[0][1], 0, 0, 0);
            acc[1][0] = __builtin_amdgcn_mfma_f32_16x16x32_bf16(wf0, xf1, acc[1][0], 0, 0, 0);
            acc[1][1] = __builtin_amdgcn_mfma_f32_16x16x32_bf16(wf1, xf1, acc[1][1], 0, 0, 0);
        }
    }

    #pragma unroll
    for (int nt = 0; nt < 2; ++nt) {
        const int nb = n0 + wn * 32 + nt * 16 + hi * 4;
        const float b0 = bias[nb + 0], b1 = bias[nb + 1];
        const float b2 = bias[nb + 2], b3 = bias[nb + 3];
        const int which = nb / C;
        const int co = nb - which * C;
        const int h = co / dh;
        const int dd = co - h * dh;
        u16* dst = (which == 0) ? (att ? Qb : Qa)
                 : (which == 1) ? (att ? Kb : Ka) : (att ? Vb : Va);
        const float sc = (which == 0) ? qscale : 1.0f;
        #pragma unroll
        for (int mt = 0; mt < 2; ++mt) {
            int m = m0 + wm * 32 + mt * 16 + lo;
            int b_ = m / L; int l = m - b_ * L;
            u16x4 pk = {f2bf((acc[mt][nt][0] + b0) * sc),
                        f2bf((acc[mt][nt][1] + b1) * sc),
                        f2bf((acc[mt][nt][2] + b2) * sc),
                        f2bf((acc[mt][nt][3] + b3) * sc)};
            *(u16x4*)&dst[((size_t)(b_ * NHEADS + h) * L + l) * dh + dd] = pk;
        }
    }
}

// ---------------------------------------------------------------------------
// Fused out_proj GEMM, both attentions: out bf16 [m][C].
// ---------------------------------------------------------------------------
__global__ __launch_bounds__(256) void gemm_proj(
    const u16* __restrict__ Ana, const u16* __restrict__ Anb,
    const float* __restrict__ w12, const float* __restrict__ b12,
    const float* __restrict__ w13, const float* __restrict__ b13,
    u16* __restrict__ A1t, u16* __restrict__ A2t,
    int M, int C, int gx, int perAtt)
{
    const int att = blockIdx.x / perAtt;
    const int r = blockIdx.x - att * perAtt;
    const int n0 = (r % gx) * 64;
    const int m0 = (r / gx) * 64;
    const int K = C;
    __shared__ __align__(16) u16 Xs[64][72];
    __shared__ __align__(16) u16 Ws[64][72];
    const int tid = threadIdx.x;
    const int wid = tid >> 6, lane = tid & 63;
    const int lo = lane & 15, hi = lane >> 4;
    const int wm = wid >> 1, wn = wid & 1;

    const u16* __restrict__ X = att ? Anb : Ana;
    const float* __restrict__ W = att ? w13 : w12;
    const float* __restrict__ bias = att ? b13 : b12;
    u16* __restrict__ dst = att ? A2t : A1t;

    f32x4 acc[2][2];
    #pragma unroll
    for (int i = 0; i < 2; ++i)
        #pragma unroll
        for (int j = 0; j < 2; ++j)
            #pragma unroll
            for (int rr = 0; rr < 4; ++rr) acc[i][j][rr] = 0.f;

    u16x8 xreg[2];
    f32x4 wreg[4];

    auto load_x = [&](int k0) {
        #pragma unroll
        for (int p = 0; p < 2; ++p) {
            int c = tid + p * 256;
            int row = c >> 3, kc = c & 7;
            xreg[p] = *(const u16x8*)&X[(size_t)(m0 + row) * K + k0 + kc * 8];
        }
    };
    auto load_w = [&](int k0) {
        #pragma unroll
        for (int p = 0; p < 4; ++p) {
            int c = tid + p * 256;
            int row = c >> 4, kc = c & 15;
            wreg[p] = *(const f32x4*)&W[(size_t)(n0 + row) * K + k0 + kc * 4];
        }
    };

    load_x(0);
    load_w(0);
    const int ns = K / 64;
    for (int s = 0; s < ns; ++s) {
        __syncthreads();
        #pragma unroll
        for (int p = 0; p < 2; ++p) {
            int c = tid + p * 256;
            int row = c >> 3, kc = c & 7;
            *(u16x8*)&Xs[row][kc * 8] = xreg[p];
        }
        #pragma unroll
        for (int p = 0; p < 4; ++p) {
            int c = tid + p * 256;
            int row = c >> 4, kc = c & 15;
            u16x4 cv = {f2bf(wreg[p][0]), f2bf(wreg[p][1]),
                        f2bf(wreg[p][2]), f2bf(wreg[p][3])};
            *(u16x4*)&Ws[row][kc * 4] = cv;
        }
        __syncthreads();
        if (s + 1 < ns) { load_x((s + 1) * 64); load_w((s + 1) * 64); }
        #pragma unroll
        for (int kk = 0; kk < 2; ++kk) {
            short8 wf0 = *(const short8*)&Ws[wn * 32 + lo][kk * 32 + hi * 8];
            short8 wf1 = *(const short8*)&Ws[wn * 32 + 16 + lo][kk * 32 + hi * 8];
            short8 xf0 = *(const short8*)&Xs[wm * 32 + lo][kk * 32 + hi * 8];
            short8 xf1 = *(const short8*)&Xs[wm * 32 + 16 + lo][kk * 32 + hi * 8];
            acc[0][0] = __builtin_amdgcn_mfma_f32_16x16x32_bf16(wf0, xf0, acc[0][0], 0, 0, 0);
            acc[0][1] = __builtin_amdgcn_mfma_f32_16x16x32_bf16(wf1, xf0, acc[0][1], 0, 0, 0);
            acc[1][0] = __builtin_amdgcn_mfma_f32_16x16x32_bf16(wf0, xf1, acc[1][0], 0, 0, 0);
            acc[1][1] = __builtin_amdgcn_mfma_f32_16x16x32_bf16(wf1, xf1, acc[1][1], 0, 0, 0);
        }
    }

    #pragma unroll
    for (int nt = 0; nt < 2; ++nt) {
        const int nb = n0 + wn * 32 + nt * 16 + hi * 4;
        const float b0 = bias[nb + 0], b1 = bias[nb + 1];
        const float b2 = bias[nb + 2], b3 = bias[nb + 3];
        #pragma unroll
        for (int mt = 0; mt < 2; ++mt) {
            int m = m0 + wm * 32 + mt * 16 + lo;
            u16x4 pk = {f2bf(acc[mt][nt][0] + b0), f2bf(acc[mt][nt][1] + b1),
                        f2bf(acc[mt][nt][2] + b2), f2bf(acc[mt][nt][3] + b3)};
            *(u16x4*)&dst[(size_t)m * C + nb] = pk;
        }
    }
}

// ---------------------------------------------------------------------------
// Squeeze GEMM: X per-k-block from {f1t, A1t, A2t}; out fp32 [b][n][l].
// ---------------------------------------------------------------------------
__global__ __launch_bounds__(256) void gemm_squeeze(
    const u16* __restrict__ X0, const u16* __restrict__ X1,
    const u16* __restrict__ X2,
    const float* __restrict__ W, const float* __restrict__ bias,
    float* __restrict__ out, int M, int C, int L)
{
    const int n0 = blockIdx.x * 64;
    const int m0 = blockIdx.y * 64;
    const int K = 3 * C;
    __shared__ __align__(16) u16 Xs[64][72];
    __shared__ __align__(16) u16 Ws[64][72];
    const int tid = threadIdx.x;
    const int wid = tid >> 6, lane = tid & 63;
    const int lo = lane & 15, hi = lane >> 4;
    const int wm = wid >> 1, wn = wid & 1;

    f32x4 acc[2][2];
    #pragma unroll
    for (int i = 0; i < 2; ++i)
        #pragma unroll
        for (int j = 0; j < 2; ++j)
            #pragma unroll
            for (int rr = 0; rr < 4; ++rr) acc[i][j][rr] = 0.f;

    u16x8 xreg[2];
    f32x4 wreg[4];

    auto load_x = [&](int k0) {
        int wk = k0 / C;
        const u16* src = (wk == 0) ? X0 : (wk == 1 ? X1 : X2);
        int kl = k0 - wk * C;
        #pragma unroll
        for (int p = 0; p < 2; ++p) {
            int c = tid + p * 256;
            int row = c >> 3, kc = c & 7;
            xreg[p] = *(const u16x8*)&src[(size_t)(m0 + row) * C + kl + kc * 8];
        }
    };
    auto load_w = [&](int k0) {
        #pragma unroll
        for (int p = 0; p < 4; ++p) {
            int c = tid + p * 256;
            int row = c >> 4, kc = c & 15;
            wreg[p] = *(const f32x4*)&W[(size_t)(n0 + row) * K + k0 + kc * 4];
        }
    };

    load_x(0);
    load_w(0);
    const int ns = K / 64;
    for (int s = 0; s < ns; ++s) {
        __syncthreads();
        #pragma unroll
        for (int p = 0; p < 2; ++p) {
            int c = tid + p * 256;
            int row = c >> 3, kc = c & 7;
            *(u16x8*)&Xs[row][kc * 8] = xreg[p];
        }
        #pragma unroll
        for (int p = 0; p < 4; ++p) {
            int c = tid + p * 256;
            int row = c >> 4, kc = c & 15;
            u16x4 cv = {f2bf(wreg[p][0]), f2bf(wreg[p][1]),
                        f2bf(wreg[p][2]), f2bf(wreg[p][3])};
            *(u16x4*)&Ws[row][kc * 4] = cv;
        }
        __syncthreads();
        if (s + 1 < ns) { load_x((s + 1) * 64); load_w((s + 1) * 64); }
        #pragma unroll
        for (int kk = 0; kk < 2; ++kk) {
            short8 wf0 = *(const short8*)&Ws[wn * 32 + lo][kk * 32 + hi * 8];
            short8 wf1 = *(const short8*)&Ws[wn * 32 + 16 + lo][kk * 32 + hi * 8];
            short8 xf0 = *(const short8*)&Xs[wm * 32 + lo][kk * 32 + hi * 8];
            short8 xf1 = *(const short8*)&Xs[wm * 32 + 16 + lo][kk * 32 + hi * 8];
            acc[0][0] = __builtin_amdgcn_mfma_f32_16x16x32_bf16(wf0, xf0, acc[0][0], 0, 0, 0);
            acc[0][1] = __builtin_amdgcn_mfma_f32_16x16x32_bf16(wf1, xf0, acc[0][1], 0, 0, 0);
            acc[1][0] = __builtin_amdgcn_mfma_f32_16x16x32_bf16(wf0, xf1, acc[1][0], 0, 0, 0);
            acc[1][1] = __builtin_amdgcn_mfma_f32_16x16x32_bf16(wf1, xf1, acc[1][1], 0, 0, 0);
        }
    }

    #pragma unroll
    for (int nt = 0; nt < 2; ++nt) {
        const int nb = n0 + wn * 32 + nt * 16 + hi * 4;
        const float b0 = bias[nb + 0], b1 = bias[nb + 1];
        const float b2 = bias[nb + 2], b3 = bias[nb + 3];
        #pragma unroll
        for (int mt = 0; mt < 2; ++mt) {
            int m = m0 + wm * 32 + mt * 16 + lo;
            int b_ = m / L; int l = m - b_ * L;
            out[((size_t)(b_ * C + nb + 0)) * L + l] = acc[mt][nt][0] + b0;
            out[((size_t)(b_ * C + nb + 1)) * L + l] = acc[mt][nt][1] + b1;
            out[((size_t)(b_ * C + nb + 2)) * L + l] = acc[mt][nt][2] + b2;
            out[((size_t)(b_ * C + nb + 3)) * L + l] = acc[mt][nt][3] + b3;
        }
    }
}

// ---------------------------------------------------------------------------
// Generalized split flash: 128*NPAR threads = 2 q-groups x NPAR s-parities.
// Both attentions fused. K is NOT staged (L2-resident; A-fragments load
// straight from global — Common-mistake #7). V double-buffered in LDS
// (transposed + XOR-swizzled), ONE barrier per round; staging writes for
// round r+1 overlap PV of round r. In-register P via K=16 MFMA. Defer-max.
// NOTE: no min-waves launch bound (round-7 spill lesson).
// ---------------------------------------------------------------------------
template <int DH, int NPAR, int NQS>
__global__ __launch_bounds__(128 * NPAR) void flash_split(
    const u16* __restrict__ Q1, const u16* __restrict__ K1,
    const u16* __restrict__ V1, u16* __restrict__ O1,
    const u16* __restrict__ Q2, const u16* __restrict__ K2,
    const u16* __restrict__ V2, u16* __restrict__ O2, int L, int S)
{
    constexpr int KB = 64;
    constexpr int QW = 16 * NQS;
    constexpr int QB = 2 * QW;
    constexpr int NKK = DH / 32;
    constexpr int NNT = DH / 16;
    constexpr int DG = DH / 8;          // 8-col groups per row
    constexpr int SLOTS = DG / 8;       // staging slots per thread
    constexpr int SZ_VT = 2 * NPAR * DH * KB * 2;
    constexpr int MST = DH + 4;
    constexpr int P = NPAR - 1;

    __shared__ __align__(16) char smem[SZ_VT];
    u16 (*Vt)[NPAR][DH][KB] = (u16 (*)[NPAR][DH][KB])smem;
    float* MrgAcc = (float*)smem;                         // [2*P][QW][MST]
    float* MrgML  = (float*)(smem + (size_t)2 * P * QW * MST * 4);

    const int nQT = L / QB;
    const int perAtt = 2 * NHEADS * nQT;
    const int att = blockIdx.x / perAtt;
    const int rem = blockIdx.x - att * perAtt;
    const int qt = rem % nQT;
    const int bh = rem / nQT;
    const u16* __restrict__ Q = att ? Q2 : Q1;
    const u16* __restrict__ K = att ? K2 : K1;
    const u16* __restrict__ V = att ? V2 : V1;
    u16* __restrict__ O = att ? O2 : O1;

    const int tid = threadIdx.x;
    const int w = tid >> 6;
    const int lane = tid & 63;
    const int lo = lane & 15, hi = lane >> 4;
    const int qg = w & 1, par = w >> 1;
    const int q0 = qt * QB + qg * QW;

    short8 qf[NQS][NKK];
    #pragma unroll
    for (int qs = 0; qs < NQS; ++qs)
        #pragma unroll
        for (int kk = 0; kk < NKK; ++kk)
            qf[qs][kk] = *(const short8*)&Q[((size_t)bh * L + q0 + qs * 16 + lo) * DH + kk * 32 + hi * 8];

    f32x4 acc[NQS][NNT];
    #pragma unroll
    for (int qs = 0; qs < NQS; ++qs)
        #pragma unroll
        for (int nt = 0; nt < NNT; ++nt)
            #pragma unroll
            for (int r = 0; r < 4; ++r) acc[qs][nt][r] = 0.f;
    float m_i[NQS], l_i[NQS];
    #pragma unroll
    for (int qs = 0; qs < NQS; ++qs) { m_i[qs] = -1e30f; l_i[qs] = 0.f; }

    const u16* Kbase = K + (size_t)bh * S * DH;
    const u16* Vbase = V + (size_t)bh * S * DH;

    // V staging: thread stages tile-slot pt; SLOTS (s,d) units of 4 rows x 8 d
    const int pt = tid >> 7;
    const int u = tid & 127;
    int dV0[SLOTS], sV0[SLOTS];
    #pragma unroll
    for (int z = 0; z < SLOTS; ++z) {
        int e = u + z * 128;
        dV0[z] = (e % DG) * 8;
        sV0[z] = (e / DG) * 4;
    }

    u16x8 vreg[SLOTS][4];

    auto loadslots = [&](int r) {
        const u16* Vp = Vbase + (size_t)(NPAR * r + pt) * KB * DH;
        #pragma unroll
        for (int z = 0; z < SLOTS; ++z)
            #pragma unroll
            for (int si = 0; si < 4; ++si)
                vreg[z][si] = *(const u16x8*)&Vp[(size_t)(sV0[z] + si) * DH + dV0[z]];
    };
    auto writeslots = [&](int buf) {
        #pragma unroll
        for (int z = 0; z < SLOTS; ++z)
            #pragma unroll
            for (int j = 0; j < 8; ++j) {
                int d = dV0[z] + j;
                int g = ((d >> 3) ^ d) & 7;
                int scol = (sV0[z] & 7) | ((((sV0[z] >> 3) ^ g) & 7) << 3);
                u16x4 wj = {vreg[z][0][j], vreg[z][1][j], vreg[z][2][j], vreg[z][3][j]};
                *(u16x4*)&Vt[buf][pt][d][scol] = wj;
            }
    };

    const int NR = S / (KB * NPAR);

    loadslots(0);
    writeslots(0);
    __syncthreads();
    if (1 < NR) loadslots(1);

    for (int r = 0; r < NR; ++r) {
        const int cur = r & 1;

        // ---- QK^T (swapped), K straight from global (L2-resident)
        const u16* Kt = Kbase + (size_t)(NPAR * r + par) * KB * DH;
        f32x4 sacc[4][NQS];
        #pragma unroll
        for (int st = 0; st < 4; ++st)
            #pragma unroll
            for (int qs = 0; qs < NQS; ++qs)
                #pragma unroll
                for (int rr = 0; rr < 4; ++rr) sacc[st][qs][rr] = 0.f;
        #pragma unroll
        for (int st = 0; st < 4; ++st) {
            #pragma unroll
            for (int kk = 0; kk < NKK; ++kk) {
                short8 a = *(const short8*)&Kt[(size_t)(st * 16 + lo) * DH + kk * 32 + hi * 8];
                #pragma unroll
                for (int qs = 0; qs < NQS; ++qs)
                    sacc[st][qs] = __builtin_amdgcn_mfma_f32_16x16x32_bf16(
                        a, qf[qs][kk], sacc[st][qs], 0, 0, 0);
            }
        }

        // ---- softmax prologue: row max, defer-max, acc rescale
        float mn[NQS], ts[NQS];
        #pragma unroll
        for (int qs = 0; qs < NQS; ++qs) {
            float tm = -1e30f;
            #pragma unroll
            for (int st = 0; st < 4; ++st)
                #pragma unroll
                for (int rr = 0; rr < 4; ++rr) tm = fmaxf(tm, sacc[st][qs][rr]);
            tm = fmaxf(tm, __shfl_xor(tm, 16));
            tm = fmaxf(tm, __shfl_xor(tm, 32));
            const bool grow = __any(tm > m_i[qs] + 8.0f);
            mn[qs] = grow ? fmaxf(m_i[qs], tm) : m_i[qs];
            ts[qs] = 0.f;
            if (grow) {
                float alpha = __builtin_amdgcn_exp2f(m_i[qs] - mn[qs]);
                m_i[qs] = mn[qs];
                l_i[qs] *= alpha;
                float ar[4];
                #pragma unroll
                for (int rr = 0; rr < 4; ++rr) ar[rr] = __shfl(alpha, hi * 4 + rr);
                #pragma unroll
                for (int nt = 0; nt < NNT; ++nt)
                    #pragma unroll
                    for (int rr = 0; rr < 4; ++rr) acc[qs][nt][rr] *= ar[rr];
            }
        }

        // ---- stage round r+1's V into the other buffer (overlaps PV)
        if (r + 1 < NR) writeslots(cur ^ 1);

        // ---- fused exp + PV per 16-col strip, Vt[cur]
        __builtin_amdgcn_s_setprio(1);
        #pragma unroll
        for (int st = 0; st < 4; ++st) {
            short4v pa_[NQS];
            #pragma unroll
            for (int qs = 0; qs < NQS; ++qs) {
                float p0 = __builtin_amdgcn_exp2f(sacc[st][qs][0] - mn[qs]);
                float p1 = __builtin_amdgcn_exp2f(sacc[st][qs][1] - mn[qs]);
                float p2 = __builtin_amdgcn_exp2f(sacc[st][qs][2] - mn[qs]);
                float p3 = __builtin_amdgcn_exp2f(sacc[st][qs][3] - mn[qs]);
                ts[qs] += (p0 + p1) + (p2 + p3);
                short4v pk = {(short)f2bf(p0), (short)f2bf(p1),
                              (short)f2bf(p2), (short)f2bf(p3)};
                pa_[qs] = pk;
            }
            const int s0 = st * 16 + hi * 4;
            #pragma unroll
            for (int nt = 0; nt < NNT; ++nt) {
                int d = nt * 16 + lo;
                int g = ((d >> 3) ^ d) & 7;
                int scol = (s0 & 7) | ((((s0 >> 3) ^ g) & 7) << 3);
                short4v vb = *(const short4v*)&Vt[cur][par][d][scol];
                #pragma unroll
                for (int qs = 0; qs < NQS; ++qs)
                    acc[qs][nt] = __builtin_amdgcn_mfma_f32_16x16x16bf16_1k(
                        pa_[qs], vb, acc[qs][nt], 0, 0, 0);
            }
        }
        __builtin_amdgcn_s_setprio(0);

        // ---- finalize l
        #pragma unroll
        for (int qs = 0; qs < NQS; ++qs) {
            float t2 = ts[qs];
            t2 += __shfl_xor(t2, 16);
            t2 += __shfl_xor(t2, 32);
            l_i[qs] += t2;
        }

        __syncthreads();
        if (r + 2 < NR) loadslots(r + 2);
    }

    // ---- NPAR-way merge epilogue (MrgAcc/MrgML alias the Vt region)
    const int b_ = bh / NHEADS, h_ = bh % NHEADS;
    if (par != 0) {
        const int mi = qg * P + par - 1;
        float* ma = MrgAcc + (size_t)mi * QW * MST;
        #pragma unroll
        for (int qs = 0; qs < NQS; ++qs) {
            #pragma unroll
            for (int nt = 0; nt < NNT; ++nt)
                #pragma unroll
                for (int rr = 0; rr < 4; ++rr)
                    ma[(size_t)(qs * 16 + hi * 4 + rr) * MST + nt * 16 + lo] = acc[qs][nt][rr];
            if (hi == 0) {
                MrgML[(mi * 2 + 0) * QW + qs * 16 + lo] = m_i[qs];
                MrgML[(mi * 2 + 1) * QW + qs * 16 + lo] = l_i[qs];
            }
        }
    }
    __syncthreads();
    if (par == 0) {
        #pragma unroll
        for (int qs = 0; qs < NQS; ++qs) {
            float mp[P > 0 ? P : 1], lp[P > 0 ? P : 1];
            float mt = m_i[qs];
            #pragma unroll
            for (int p = 0; p < P; ++p) {
                mp[p] = MrgML[((qg * P + p) * 2 + 0) * QW + qs * 16 + lo];
                lp[p] = MrgML[((qg * P + p) * 2 + 1) * QW + qs * 16 + lo];
                mt = fmaxf(mt, mp[p]);
            }
            float c0 = __builtin_amdgcn_exp2f(m_i[qs] - mt);
            float lt = c0 * l_i[qs];
            float cp[P > 0 ? P : 1];
            #pragma unroll
            for (int p = 0; p < P; ++p) {
                cp[p] = __builtin_amdgcn_exp2f(mp[p] - mt);
                lt += cp[p] * lp[p];
            }
            float linv = 1.0f / lt;
            c0 *= linv;
            #pragma unroll
            for (int p = 0; p < P; ++p) cp[p] *= linv;
            float c0r[4], cpr[P > 0 ? P : 1][4];
            #pragma unroll
            for (int rr = 0; rr < 4; ++rr) {
                c0r[rr] = __shfl(c0, hi * 4 + rr);
                #pragma unroll
                for (int p = 0; p < P; ++p) cpr[p][rr] = __shfl(cp[p], hi * 4 + rr);
            }
            #pragma unroll
            for (int nt = 0; nt < NNT; ++nt)
                #pragma unroll
                for (int rr = 0; rr < 4; ++rr) {
                    int q = qs * 16 + hi * 4 + rr;
                    float ov = acc[qs][nt][rr] * c0r[rr];
                    #pragma unroll
                    for (int p = 0; p < P; ++p)
                        ov += MrgAcc[((size_t)(qg * P + p) * QW + q) * MST + nt * 16 + lo] * cpr[p][rr];
                    O[(((size_t)b_ * L + q0 + q) * NHEADS + h_) * DH + nt * 16 + lo] = f2bf(ov);
                }
        }
    }
}

// ---------------------------------------------------------------------------
// Level-3 flash (unchanged from round 8): 128 threads, 2 waves, in-reg P.
// ---------------------------------------------------------------------------
template <int DH, int NQS, int PRE>
__global__ __launch_bounds__(128) void flash_mfma(
    const u16* __restrict__ Q1, const u16* __restrict__ K1,
    const u16* __restrict__ V1, u16* __restrict__ O1,
    const u16* __restrict__ Q2, const u16* __restrict__ K2,
    const u16* __restrict__ V2, u16* __restrict__ O2, int L, int S)
{
    constexpr int KB = 64;
    constexpr int QW = NQS * 16;
    constexpr int QB = 2 * QW;
    constexpr int DH8 = DH / 8;
    constexpr int KC = (KB * DH8) / 128;
    constexpr int VU = (16 * DH8) / 128;
    constexpr int NKK = DH / 32;
    constexpr int NNT = DH / 16;

    __shared__ __align__(16) u16 Ks[KB][DH + 8];
    __shared__ __align__(16) u16 Vt[DH][KB];

    const int nQT = L / QB;
    const int perAtt = 2 * NHEADS * nQT;
    const int att = blockIdx.x / perAtt;
    const int rem = blockIdx.x - att * perAtt;
    const int qt = rem % nQT;
    const int bh = rem / nQT;
    const u16* __restrict__ Q = att ? Q2 : Q1;
    const u16* __restrict__ K = att ? K2 : K1;
    const u16* __restrict__ V = att ? V2 : V1;
    u16* __restrict__ O = att ? O2 : O1;

    const int tid = threadIdx.x;
    const int wv = tid >> 6;
    const int lane = tid & 63;
    const int lo = lane & 15;
    const int hi = lane >> 4;
    const int q0 = qt * QB + wv * QW;

    short8 qf[NQS][NKK];
    #pragma unroll
    for (int qs = 0; qs < NQS; ++qs)
        #pragma unroll
        for (int kk = 0; kk < NKK; ++kk)
            qf[qs][kk] = *(const short8*)&Q[((size_t)bh * L + q0 + qs * 16 + lo) * DH + kk * 32 + hi * 8];

    f32x4 acc[NQS][NNT];
    #pragma unroll
    for (int qs = 0; qs < NQS; ++qs)
        #pragma unroll
        for (int nt = 0; nt < NNT; ++nt)
            #pragma unroll
            for (int r = 0; r < 4; ++r) acc[qs][nt][r] = 0.f;
    float m_i[NQS], l_i[NQS];
    #pragma unroll
    for (int qs = 0; qs < NQS; ++qs) { m_i[qs] = -1e30f; l_i[qs] = 0.f; }

    const int NT = S / KB;
    u16x8 kreg[PRE ? KC : 1];
    u16x8 vreg[PRE ? VU : 1][4];

    const u16* Kbase = K + (size_t)bh * S * DH;
    const u16* Vbase = V + (size_t)bh * S * DH;

    auto vwrite = [&](int d, int s0, u16x4 wj) {
        int g = ((d >> 3) ^ d) & 7;
        int scol = (s0 & 7) | ((((s0 >> 3) ^ g) & 7) << 3);
        *(u16x4*)&Vt[d][scol] = wj;
    };

    if (PRE) {
        #pragma unroll
        for (int i = 0; i < KC; ++i) {
            int idx = tid + i * 128;
            kreg[i] = *(const u16x8*)&Kbase[(size_t)(idx / DH8) * DH + (idx % DH8) * 8];
        }
        #pragma unroll
        for (int u = 0; u < VU; ++u) {
            int uu = tid + u * 128;
            int d0 = (uu % DH8) * 8, s0 = (uu / DH8) * 4;
            #pragma unroll
            for (int si = 0; si < 4; ++si)
                vreg[u][si] = *(const u16x8*)&Vbase[(size_t)(s0 + si) * DH + d0];
        }
    }

    for (int t = 0; t < NT; ++t) {
        __syncthreads();
        if (PRE) {
            #pragma unroll
            for (int i = 0; i < KC; ++i) {
                int idx = tid + i * 128;
                *(u16x8*)&Ks[idx / DH8][(idx % DH8) * 8] = kreg[i];
            }
            #pragma unroll
            for (int u = 0; u < VU; ++u) {
                int uu = tid + u * 128;
                int d0 = (uu % DH8) * 8, s0 = (uu / DH8) * 4;
                #pragma unroll
                for (int j = 0; j < 8; ++j) {
                    u16x4 wj = {vreg[u][0][j], vreg[u][1][j], vreg[u][2][j], vreg[u][3][j]};
                    vwrite(d0 + j, s0, wj);
                }
            }
        } else {
            const u16* Kp = Kbase + (size_t)t * KB * DH;
            const u16* Vp = Vbase + (size_t)t * KB * DH;
            #pragma unroll
            for (int i = 0; i < KC; ++i) {
                int idx = tid + i * 128;
                *(u16x8*)&Ks[idx / DH8][(idx % DH8) * 8] =
                    *(const u16x8*)&Kp[(size_t)(idx / DH8) * DH + (idx % DH8) * 8];
            }
            #pragma unroll
            for (int u = 0; u < VU; ++u) {
                int uu = tid + u * 128;
                int d0 = (uu % DH8) * 8, s0 = (uu / DH8) * 4;
                u16x8 v0 = *(const u16x8*)&Vp[(size_t)(s0 + 0) * DH + d0];
                u16x8 v1 = *(const u16x8*)&Vp[(size_t)(s0 + 1) * DH + d0];
                u16x8 v2 = *(const u16x8*)&Vp[(size_t)(s0 + 2) * DH + d0];
                u16x8 v3 = *(const u16x8*)&Vp[(size_t)(s0 + 3) * DH + d0];
                #pragma unroll
                for (int j = 0; j < 8; ++j) {
                    u16x4 wj = {v0[j], v1[j], v2[j], v3[j]};
                    vwrite(d0 + j, s0, wj);
                }
            }
        }
        __syncthreads();

        if (PRE && t + 1 < NT) {
            const u16* Kp = Kbase + (size_t)(t + 1) * KB * DH;
            const u16* Vp = Vbase + (size_t)(t + 1) * KB * DH;
            #pragma unroll
            for (int i = 0; i < KC; ++i) {
                int idx = tid + i * 128;
                kreg[i] = *(const u16x8*)&Kp[(size_t)(idx / DH8) * DH + (idx % DH8) * 8];
            }
            #pragma unroll
            for (int u = 0; u < VU; ++u) {
                int uu = tid + u * 128;
                int d0 = (uu % DH8) * 8, s0 = (uu / DH8) * 4;
                #pragma unroll
                for (int si = 0; si < 4; ++si)
                    vreg[u][si] = *(const u16x8*)&Vp[(size_t)(s0 + si) * DH + d0];
            }
        }

        f32x4 sacc[4][NQS];
        #pragma unroll
        for (int st = 0; st < 4; ++st)
            #pragma unroll
            for (int qs = 0; qs < NQS; ++qs)
                #pragma unroll
                for (int r = 0; r < 4; ++r) sacc[st][qs][r] = 0.f;
        #pragma unroll
        for (int st = 0; st < 4; ++st) {
            #pragma unroll
            for (int kk = 0; kk < NKK; ++kk) {
                short8 a = *(const short8*)&Ks[st * 16 + lo][kk * 32 + hi * 8];
                #pragma unroll
                for (int qs = 0; qs < NQS; ++qs)
                    sacc[st][qs] = __builtin_amdgcn_mfma_f32_16x16x32_bf16(
                        a, qf[qs][kk], sacc[st][qs], 0, 0, 0);
            }
        }

        float mn[NQS], ts[NQS];
        #pragma unroll
        for (int qs = 0; qs < NQS; ++qs) {
            float tm = -1e30f;
            #pragma unroll
            for (int st = 0; st < 4; ++st)
                #pragma unroll
                for (int r = 0; r < 4; ++r) tm = fmaxf(tm, sacc[st][qs][r]);
            tm = fmaxf(tm, __shfl_xor(tm, 16));
            tm = fmaxf(tm, __shfl_xor(tm, 32));
            const bool grow = __any(tm > m_i[qs] + 8.0f);
            mn[qs] = grow ? fmaxf(m_i[qs], tm) : m_i[qs];
            ts[qs] = 0.f;
            if (grow) {
                float alpha = __builtin_amdgcn_exp2f(m_i[qs] - mn[qs]);
                m_i[qs] = mn[qs];
                l_i[qs] *= alpha;
                float ar[4];
                #pragma unroll
                for (int r = 0; r < 4; ++r) ar[r] = __shfl(alpha, hi * 4 + r);
                #pragma unroll
                for (int nt = 0; nt < NNT; ++nt)
                    #pragma unroll
                    for (int r = 0; r < 4; ++r) acc[qs][nt][r] *= ar[r];
            }
        }

        #pragma unroll
        for (int st = 0; st < 4; ++st) {
            short4v pa_[NQS];
            #pragma unroll
            for (int qs = 0; qs < NQS; ++qs) {
                float p0 = __builtin_amdgcn_exp2f(sacc[st][qs][0] - mn[qs]);
                float p1 = __builtin_amdgcn_exp2f(sacc[st][qs][1] - mn[qs]);
                float p2 = __builtin_amdgcn_exp2f(sacc[st][qs][2] - mn[qs]);
                float p3 = __builtin_amdgcn_exp2f(sacc[st][qs][3] - mn[qs]);
                ts[qs] += (p0 + p1) + (p2 + p3);
                short4v pk = {(short)f2bf(p0), (short)f2bf(p1),
                              (short)f2bf(p2), (short)f2bf(p3)};
                pa_[qs] = pk;
            }
            const int s0 = st * 16 + hi * 4;
            #pragma unroll
            for (int nt = 0; nt < NNT; ++nt) {
                int d = nt * 16 + lo;
                int g = ((d >> 3) ^ d) & 7;
                int scol = (s0 & 7) | ((((s0 >> 3) ^ g) & 7) << 3);
                short4v vb = *(const short4v*)&Vt[d][scol];
                #pragma unroll
                for (int qs = 0; qs < NQS; ++qs)
                    acc[qs][nt] = __builtin_amdgcn_mfma_f32_16x16x16bf16_1k(
                        pa_[qs], vb, acc[qs][nt], 0, 0, 0);
            }
        }

        #pragma unroll
        for (int qs = 0; qs < NQS; ++qs) {
            float t2 = ts[qs];
            t2 += __shfl_xor(t2, 16);
            t2 += __shfl_xor(t2, 32);
            l_i[qs] += t2;
        }
    }

    const int b_ = bh / NHEADS, h_ = bh % NHEADS;
    #pragma unroll
    for (int qs = 0; qs < NQS; ++qs) {
        float inv = 1.0f / l_i[qs];
        float ir[4];
        #pragma unroll
        for (int r = 0; r < 4; ++r) ir[r] = __shfl(inv, hi * 4 + r);
        #pragma unroll
        for (int nt = 0; nt < NNT; ++nt)
            #pragma unroll
            for (int r = 0; r < 4; ++r) {
                int l = q0 + qs * 16 + hi * 4 + r;
                O[(((size_t)b_ * L + l) * NHEADS + h_) * DH + nt * 16 + lo] =
                    f2bf(acc[qs][nt][r] * ir[r]);
            }
    }
}

// ---------------------------------------------------------------------------

extern "C" void kernel_launch(void* const* d_in, const int* in_sizes, int n_in,
                              void* d_out, int out_size, void* d_ws, size_t ws_size,
                              hipStream_t stream)
{
    static const int CHs[4] = {64, 128, 256, 512};
    static const int HWs[4] = {128, 64, 32, 16};

    const float* f1[4] = {(const float*)d_in[0], (const float*)d_in[1],
                          (const float*)d_in[2], (const float*)d_in[3]};
    const float* f2[4] = {nullptr, (const float*)d_in[4], (const float*)d_in[6],
                          (const float*)d_in[8]};
    const float* f3[4] = {nullptr, (const float*)d_in[5], (const float*)d_in[7],
                          (const float*)d_in[9]};

    // level 0: pass-through
    size_t out0_elems = (size_t)in_sizes[0];
    hipMemcpyAsync(d_out, d_in[0], out0_elems * sizeof(float),
                   hipMemcpyDeviceToDevice, stream);

    // workspace: 11 slots of 2*4096*128 u16 (22 MB), reused per level.
    const size_t SL = (size_t)2 * 4096 * 128;
    u16* wsu = (u16*)d_ws;
    u16* f1t = wsu + 0 * SL;
    u16* f2t = wsu + 1 * SL;   // aliases Ana after qkv
    u16* f3t = wsu + 2 * SL;   // aliases Anb after qkv
    u16* Qa  = wsu + 3 * SL;
    u16* Ka  = wsu + 4 * SL;
    u16* Va  = wsu + 5 * SL;
    u16* Qb  = wsu + 6 * SL;
    u16* Kb  = wsu + 7 * SL;
    u16* Vb  = wsu + 8 * SL;
    u16* A1t = wsu + 9 * SL;
    u16* A2t = wsu + 10 * SL;
    u16* Ana = f2t;
    u16* Anb = f3t;

    const float LOG2E = 1.44269504088896340736f;

    size_t outOff = out0_elems;
    for (int lvl = 1; lvl <= 3; ++lvl) {
        const int C = CHs[lvl];
        const int Hs = HWs[lvl];
        const int L = Hs * Hs;
        const int dh = C / NHEADS;
        const int M = 2 * L;  // B*L
        const float qscale = LOG2E / sqrtf((float)dh);
        const int bi = 10 + (lvl - 1) * 10;
        const float* a12w  = (const float*)d_in[bi + 0];
        const float* a12b  = (const float*)d_in[bi + 1];
        const float* a12ow = (const float*)d_in[bi + 2];
        const float* a12ob = (const float*)d_in[bi + 3];
        const float* a13w  = (const float*)d_in[bi + 4];
        const float* a13b  = (const float*)d_in[bi + 5];
        const float* a13ow = (const float*)d_in[bi + 6];
        const float* a13ob = (const float*)d_in[bi + 7];
        const float* sqw   = (const float*)d_in[bi + 8];
        const float* sqb   = (const float*)d_in[bi + 9];

        // 1) transpose f1/f2/f3 -> bf16 [b, l, c]
        dim3 tg(L / 32, C / 32, 6);
        transpose_bf16_kernel<<<tg, 256, 0, stream>>>(f1[lvl], f2[lvl], f3[lvl],
                                                      f1t, f2t, f3t, C, L);

        // 2) fused qkv (both attentions)
        const int gx = 3 * C / 64;
        const int perAtt = gx * (M / 64);
        gemm_qkv<<<2 * perAtt, 256, 0, stream>>>(
            f1t, f2t, f3t, a12w, a12b, a13w, a13b,
            Qa, Ka, Va, Qb, Kb, Vb, M, C, L, dh, qscale, gx, perAtt);

        // 3) fused flash (both attentions)
        if (dh == 64)
            flash_split<64, 4, 2><<<2 * (2 * NHEADS) * (L / 64), 512, 0, stream>>>(
                Qa, Ka, Va, Ana, Qb, Kb, Vb, Anb, L, L);
        else if (dh == 128)
            flash_split<128, 2, 1><<<2 * (2 * NHEADS) * (L / 32), 256, 0, stream>>>(
                Qa, Ka, Va, Ana, Qb, Kb, Vb, Anb, L, L);
        else
            flash_mfma<256, 1, 0><<<2 * (2 * NHEADS) * (L / 32), 128, 0, stream>>>(
                Qa, Ka, Va, Ana, Qb, Kb, Vb, Anb, L, L);

        // 4) fused out_proj (both attentions)
        const int gx2 = C / 64;
        const int perAtt2 = gx2 * (M / 64);
        gemm_proj<<<2 * perAtt2, 256, 0, stream>>>(
            Ana, Anb, a12ow, a12ob, a13ow, a13ob, A1t, A2t, M, C, gx2, perAtt2);

        // 5) squeeze into d_out (fp32 [b, n, l])
        dim3 gsq(C / 64, M / 64);
        gemm_squeeze<<<gsq, 256, 0, stream>>>(f1t, A1t, A2t, sqw, sqb,
                                              (float*)d_out + outOff, M, C, L);
        outOff += (size_t)2 * C * L;
    }
}

// Round 10
// 293.826 us; speedup vs baseline: 1.1515x; 1.1515x over previous
//
#include <hip/hip_runtime.h>
#include <hip/hip_bf16.h>
#include <math.h>

#define NHEADS 2

typedef unsigned short u16;
typedef __attribute__((ext_vector_type(8))) unsigned short u16x8;
typedef __attribute__((ext_vector_type(4))) unsigned short u16x4;
typedef __attribute__((ext_vector_type(8))) short short8;
typedef __attribute__((ext_vector_type(4))) short short4v;
typedef __attribute__((ext_vector_type(4))) float f32x4;

__device__ __forceinline__ u16 f2bf(float x) {
    __hip_bfloat16 h = __float2bfloat16(x);
    return __builtin_bit_cast(unsigned short, h);
}

// ---------------------------------------------------------------------------
// Transpose + bf16 convert: f [b, c, l] fp32  ->  ft [b, l, c] bf16.
// ---------------------------------------------------------------------------
__global__ __launch_bounds__(256) void transpose_bf16_kernel(
    const float* __restrict__ s0, const float* __restrict__ s1,
    const float* __restrict__ s2,
    u16* __restrict__ d0, u16* __restrict__ d1, u16* __restrict__ d2,
    int C, int L)
{
    const int z = blockIdx.z;
    const int which = z >> 1;
    const int b = z & 1;
    const float* __restrict__ src = (which == 0) ? s0 : (which == 1 ? s1 : s2);
    u16* __restrict__ dst = (which == 0) ? d0 : (which == 1 ? d1 : d2);
    const int l0 = blockIdx.x * 32;
    const int c0 = blockIdx.y * 32;
    __shared__ float Ts[32][33];
    const int t = threadIdx.x;
    const int x = t & 31, y = t >> 5;
    #pragma unroll
    for (int p = 0; p < 4; ++p)
        Ts[y + 8 * p][x] = src[((size_t)(b * C + c0 + y + 8 * p)) * L + l0 + x];
    __syncthreads();
    #pragma unroll
    for (int p = 0; p < 4; ++p)
        dst[((size_t)(b * L + l0 + y + 8 * p)) * C + c0 + x] = f2bf(Ts[x][y + 8 * p]);
}

// ---------------------------------------------------------------------------
// Fused qkv GEMM, both attentions in one launch.
// ---------------------------------------------------------------------------
__global__ __launch_bounds__(256) void gemm_qkv(
    const u16* __restrict__ f1t, const u16* __restrict__ f2t,
    const u16* __restrict__ f3t,
    const float* __restrict__ w12, const float* __restrict__ b12,
    const float* __restrict__ w13, const float* __restrict__ b13,
    u16* __restrict__ Qa, u16* __restrict__ Ka, u16* __restrict__ Va,
    u16* __restrict__ Qb, u16* __restrict__ Kb, u16* __restrict__ Vb,
    int M, int C, int L, int dh, float qscale, int gx, int perAtt)
{
    const int att = blockIdx.x / perAtt;
    const int r = blockIdx.x - att * perAtt;
    const int n0 = (r % gx) * 64;
    const int m0 = (r / gx) * 64;
    const int K = C;
    __shared__ __align__(16) u16 Xs[64][72];
    __shared__ __align__(16) u16 Ws[64][72];
    const int tid = threadIdx.x;
    const int wid = tid >> 6, lane = tid & 63;
    const int lo = lane & 15, hi = lane >> 4;
    const int wm = wid >> 1, wn = wid & 1;

    const u16* __restrict__ X = (n0 < C) ? f1t : (att ? f3t : f2t);
    const float* __restrict__ W = att ? w13 : w12;
    const float* __restrict__ bias = att ? b13 : b12;

    f32x4 acc[2][2];
    #pragma unroll
    for (int i = 0; i < 2; ++i)
        #pragma unroll
        for (int j = 0; j < 2; ++j)
            #pragma unroll
            for (int rr = 0; rr < 4; ++rr) acc[i][j][rr] = 0.f;

    u16x8 xreg[2];
    f32x4 wreg[4];

    auto load_x = [&](int k0) {
        #pragma unroll
        for (int p = 0; p < 2; ++p) {
            int c = tid + p * 256;
            int row = c >> 3, kc = c & 7;
            xreg[p] = *(const u16x8*)&X[(size_t)(m0 + row) * K + k0 + kc * 8];
        }
    };
    auto load_w = [&](int k0) {
        #pragma unroll
        for (int p = 0; p < 4; ++p) {
            int c = tid + p * 256;
            int row = c >> 4, kc = c & 15;
            wreg[p] = *(const f32x4*)&W[(size_t)(n0 + row) * K + k0 + kc * 4];
        }
    };

    load_x(0);
    load_w(0);
    const int ns = K / 64;
    for (int s = 0; s < ns; ++s) {
        __syncthreads();
        #pragma unroll
        for (int p = 0; p < 2; ++p) {
            int c = tid + p * 256;
            int row = c >> 3, kc = c & 7;
            *(u16x8*)&Xs[row][kc * 8] = xreg[p];
        }
        #pragma unroll
        for (int p = 0; p < 4; ++p) {
            int c = tid + p * 256;
            int row = c >> 4, kc = c & 15;
            u16x4 cv = {f2bf(wreg[p][0]), f2bf(wreg[p][1]),
                        f2bf(wreg[p][2]), f2bf(wreg[p][3])};
            *(u16x4*)&Ws[row][kc * 4] = cv;
        }
        __syncthreads();
        if (s + 1 < ns) { load_x((s + 1) * 64); load_w((s + 1) * 64); }
        #pragma unroll
        for (int kk = 0; kk < 2; ++kk) {
            short8 wf0 = *(const short8*)&Ws[wn * 32 + lo][kk * 32 + hi * 8];
            short8 wf1 = *(const short8*)&Ws[wn * 32 + 16 + lo][kk * 32 + hi * 8];
            short8 xf0 = *(const short8*)&Xs[wm * 32 + lo][kk * 32 + hi * 8];
            short8 xf1 = *(const short8*)&Xs[wm * 32 + 16 + lo][kk * 32 + hi * 8];
            acc[0][0] = __builtin_amdgcn_mfma_f32_16x16x32_bf16(wf0, xf0, acc[0][0], 0, 0, 0);
            acc[0][1] = __builtin_amdgcn_mfma_f32_16x16x32_bf16(wf1, xf0, acc[0][1], 0, 0, 0);
            acc[1][0] = __builtin_amdgcn_mfma_f32_16x16x32_bf16(wf0, xf1, acc[1][0], 0, 0, 0);
            acc[1][1] = __builtin_amdgcn_mfma_f32_16x16x32_bf16(wf1, xf1, acc[1][1], 0, 0, 0);
        }
    }

    #pragma unroll
    for (int nt = 0; nt < 2; ++nt) {
        const int nb = n0 + wn * 32 + nt * 16 + hi * 4;
        const float b0 = bias[nb + 0], b1 = bias[nb + 1];
        const float b2 = bias[nb + 2], b3 = bias[nb + 3];
        const int which = nb / C;
        const int co = nb - which * C;
        const int h = co / dh;
        const int dd = co - h * dh;
        u16* dst = (which == 0) ? (att ? Qb : Qa)
                 : (which == 1) ? (att ? Kb : Ka) : (att ? Vb : Va);
        const float sc = (which == 0) ? qscale : 1.0f;
        #pragma unroll
        for (int mt = 0; mt < 2; ++mt) {
            int m = m0 + wm * 32 + mt * 16 + lo;
            int b_ = m / L; int l = m - b_ * L;
            u16x4 pk = {f2bf((acc[mt][nt][0] + b0) * sc),
                        f2bf((acc[mt][nt][1] + b1) * sc),
                        f2bf((acc[mt][nt][2] + b2) * sc),
                        f2bf((acc[mt][nt][3] + b3) * sc)};
            *(u16x4*)&dst[((size_t)(b_ * NHEADS + h) * L + l) * dh + dd] = pk;
        }
    }
}

// ---------------------------------------------------------------------------
// Fused out_proj GEMM, both attentions: out bf16 [m][C].
// ---------------------------------------------------------------------------
__global__ __launch_bounds__(256) void gemm_proj(
    const u16* __restrict__ Ana, const u16* __restrict__ Anb,
    const float* __restrict__ w12, const float* __restrict__ b12,
    const float* __restrict__ w13, const float* __restrict__ b13,
    u16* __restrict__ A1t, u16* __restrict__ A2t,
    int M, int C, int gx, int perAtt)
{
    const int att = blockIdx.x / perAtt;
    const int r = blockIdx.x - att * perAtt;
    const int n0 = (r % gx) * 64;
    const int m0 = (r / gx) * 64;
    const int K = C;
    __shared__ __align__(16) u16 Xs[64][72];
    __shared__ __align__(16) u16 Ws[64][72];
    const int tid = threadIdx.x;
    const int wid = tid >> 6, lane = tid & 63;
    const int lo = lane & 15, hi = lane >> 4;
    const int wm = wid >> 1, wn = wid & 1;

    const u16* __restrict__ X = att ? Anb : Ana;
    const float* __restrict__ W = att ? w13 : w12;
    const float* __restrict__ bias = att ? b13 : b12;
    u16* __restrict__ dst = att ? A2t : A1t;

    f32x4 acc[2][2];
    #pragma unroll
    for (int i = 0; i < 2; ++i)
        #pragma unroll
        for (int j = 0; j < 2; ++j)
            #pragma unroll
            for (int rr = 0; rr < 4; ++rr) acc[i][j][rr] = 0.f;

    u16x8 xreg[2];
    f32x4 wreg[4];

    auto load_x = [&](int k0) {
        #pragma unroll
        for (int p = 0; p < 2; ++p) {
            int c = tid + p * 256;
            int row = c >> 3, kc = c & 7;
            xreg[p] = *(const u16x8*)&X[(size_t)(m0 + row) * K + k0 + kc * 8];
        }
    };
    auto load_w = [&](int k0) {
        #pragma unroll
        for (int p = 0; p < 4; ++p) {
            int c = tid + p * 256;
            int row = c >> 4, kc = c & 15;
            wreg[p] = *(const f32x4*)&W[(size_t)(n0 + row) * K + k0 + kc * 4];
        }
    };

    load_x(0);
    load_w(0);
    const int ns = K / 64;
    for (int s = 0; s < ns; ++s) {
        __syncthreads();
        #pragma unroll
        for (int p = 0; p < 2; ++p) {
            int c = tid + p * 256;
            int row = c >> 3, kc = c & 7;
            *(u16x8*)&Xs[row][kc * 8] = xreg[p];
        }
        #pragma unroll
        for (int p = 0; p < 4; ++p) {
            int c = tid + p * 256;
            int row = c >> 4, kc = c & 15;
            u16x4 cv = {f2bf(wreg[p][0]), f2bf(wreg[p][1]),
                        f2bf(wreg[p][2]), f2bf(wreg[p][3])};
            *(u16x4*)&Ws[row][kc * 4] = cv;
        }
        __syncthreads();
        if (s + 1 < ns) { load_x((s + 1) * 64); load_w((s + 1) * 64); }
        #pragma unroll
        for (int kk = 0; kk < 2; ++kk) {
            short8 wf0 = *(const short8*)&Ws[wn * 32 + lo][kk * 32 + hi * 8];
            short8 wf1 = *(const short8*)&Ws[wn * 32 + 16 + lo][kk * 32 + hi * 8];
            short8 xf0 = *(const short8*)&Xs[wm * 32 + lo][kk * 32 + hi * 8];
            short8 xf1 = *(const short8*)&Xs[wm * 32 + 16 + lo][kk * 32 + hi * 8];
            acc[0][0] = __builtin_amdgcn_mfma_f32_16x16x32_bf16(wf0, xf0, acc[0][0], 0, 0, 0);
            acc[0][1] = __builtin_amdgcn_mfma_f32_16x16x32_bf16(wf1, xf0, acc[0][1], 0, 0, 0);
            acc[1][0] = __builtin_amdgcn_mfma_f32_16x16x32_bf16(wf0, xf1, acc[1][0], 0, 0, 0);
            acc[1][1] = __builtin_amdgcn_mfma_f32_16x16x32_bf16(wf1, xf1, acc[1][1], 0, 0, 0);
        }
    }

    #pragma unroll
    for (int nt = 0; nt < 2; ++nt) {
        const int nb = n0 + wn * 32 + nt * 16 + hi * 4;
        const float b0 = bias[nb + 0], b1 = bias[nb + 1];
        const float b2 = bias[nb + 2], b3 = bias[nb + 3];
        #pragma unroll
        for (int mt = 0; mt < 2; ++mt) {
            int m = m0 + wm * 32 + mt * 16 + lo;
            u16x4 pk = {f2bf(acc[mt][nt][0] + b0), f2bf(acc[mt][nt][1] + b1),
                        f2bf(acc[mt][nt][2] + b2), f2bf(acc[mt][nt][3] + b3)};
            *(u16x4*)&dst[(size_t)m * C + nb] = pk;
        }
    }
}

// ---------------------------------------------------------------------------
// Squeeze GEMM: X per-k-block from {f1t, A1t, A2t}; out fp32 [b][n][l].
// ---------------------------------------------------------------------------
__global__ __launch_bounds__(256) void gemm_squeeze(
    const u16* __restrict__ X0, const u16* __restrict__ X1,
    const u16* __restrict__ X2,
    const float* __restrict__ W, const float* __restrict__ bias,
    float* __restrict__ out, int M, int C, int L)
{
    const int n0 = blockIdx.x * 64;
    const int m0 = blockIdx.y * 64;
    const int K = 3 * C;
    __shared__ __align__(16) u16 Xs[64][72];
    __shared__ __align__(16) u16 Ws[64][72];
    const int tid = threadIdx.x;
    const int wid = tid >> 6, lane = tid & 63;
    const int lo = lane & 15, hi = lane >> 4;
    const int wm = wid >> 1, wn = wid & 1;

    f32x4 acc[2][2];
    #pragma unroll
    for (int i = 0; i < 2; ++i)
        #pragma unroll
        for (int j = 0; j < 2; ++j)
            #pragma unroll
            for (int rr = 0; rr < 4; ++rr) acc[i][j][rr] = 0.f;

    u16x8 xreg[2];
    f32x4 wreg[4];

    auto load_x = [&](int k0) {
        int wk = k0 / C;
        const u16* src = (wk == 0) ? X0 : (wk == 1 ? X1 : X2);
        int kl = k0 - wk * C;
        #pragma unroll
        for (int p = 0; p < 2; ++p) {
            int c = tid + p * 256;
            int row = c >> 3, kc = c & 7;
            xreg[p] = *(const u16x8*)&src[(size_t)(m0 + row) * C + kl + kc * 8];
        }
    };
    auto load_w = [&](int k0) {
        #pragma unroll
        for (int p = 0; p < 4; ++p) {
            int c = tid + p * 256;
            int row = c >> 4, kc = c & 15;
            wreg[p] = *(const f32x4*)&W[(size_t)(n0 + row) * K + k0 + kc * 4];
        }
    };

    load_x(0);
    load_w(0);
    const int ns = K / 64;
    for (int s = 0; s < ns; ++s) {
        __syncthreads();
        #pragma unroll
        for (int p = 0; p < 2; ++p) {
            int c = tid + p * 256;
            int row = c >> 3, kc = c & 7;
            *(u16x8*)&Xs[row][kc * 8] = xreg[p];
        }
        #pragma unroll
        for (int p = 0; p < 4; ++p) {
            int c = tid + p * 256;
            int row = c >> 4, kc = c & 15;
            u16x4 cv = {f2bf(wreg[p][0]), f2bf(wreg[p][1]),
                        f2bf(wreg[p][2]), f2bf(wreg[p][3])};
            *(u16x4*)&Ws[row][kc * 4] = cv;
        }
        __syncthreads();
        if (s + 1 < ns) { load_x((s + 1) * 64); load_w((s + 1) * 64); }
        #pragma unroll
        for (int kk = 0; kk < 2; ++kk) {
            short8 wf0 = *(const short8*)&Ws[wn * 32 + lo][kk * 32 + hi * 8];
            short8 wf1 = *(const short8*)&Ws[wn * 32 + 16 + lo][kk * 32 + hi * 8];
            short8 xf0 = *(const short8*)&Xs[wm * 32 + lo][kk * 32 + hi * 8];
            short8 xf1 = *(const short8*)&Xs[wm * 32 + 16 + lo][kk * 32 + hi * 8];
            acc[0][0] = __builtin_amdgcn_mfma_f32_16x16x32_bf16(wf0, xf0, acc[0][0], 0, 0, 0);
            acc[0][1] = __builtin_amdgcn_mfma_f32_16x16x32_bf16(wf1, xf0, acc[0][1], 0, 0, 0);
            acc[1][0] = __builtin_amdgcn_mfma_f32_16x16x32_bf16(wf0, xf1, acc[1][0], 0, 0, 0);
            acc[1][1] = __builtin_amdgcn_mfma_f32_16x16x32_bf16(wf1, xf1, acc[1][1], 0, 0, 0);
        }
    }

    #pragma unroll
    for (int nt = 0; nt < 2; ++nt) {
        const int nb = n0 + wn * 32 + nt * 16 + hi * 4;
        const float b0 = bias[nb + 0], b1 = bias[nb + 1];
        const float b2 = bias[nb + 2], b3 = bias[nb + 3];
        #pragma unroll
        for (int mt = 0; mt < 2; ++mt) {
            int m = m0 + wm * 32 + mt * 16 + lo;
            int b_ = m / L; int l = m - b_ * L;
            out[((size_t)(b_ * C + nb + 0)) * L + l] = acc[mt][nt][0] + b0;
            out[((size_t)(b_ * C + nb + 1)) * L + l] = acc[mt][nt][1] + b1;
            out[((size_t)(b_ * C + nb + 2)) * L + l] = acc[mt][nt][2] + b2;
            out[((size_t)(b_ * C + nb + 3)) * L + l] = acc[mt][nt][3] + b3;
        }
    }
}

// ---------------------------------------------------------------------------
// Generalized split flash: 128*NPAR threads = 2 q-groups x NPAR s-parities.
// Both attentions fused. K never touches LDS, but its fragments are
// REGISTER-PREFETCHED one round ahead (reload right after QK^T consumes
// them — softmax+PV+barrier hides the global latency; round-9 lesson:
// L2-resident still needs fetch-ahead). V double-buffered in LDS
// (transposed + XOR-swizzled, 0 bank conflicts), ONE barrier per round.
// In-register P via K=16 MFMA. Defer-max. No min-waves bound (round-7).
// ---------------------------------------------------------------------------
template <int DH, int NPAR, int NQS>
__global__ __launch_bounds__(128 * NPAR) void flash_split(
    const u16* __restrict__ Q1, const u16* __restrict__ K1,
    const u16* __restrict__ V1, u16* __restrict__ O1,
    const u16* __restrict__ Q2, const u16* __restrict__ K2,
    const u16* __restrict__ V2, u16* __restrict__ O2, int L, int S)
{
    constexpr int KB = 64;
    constexpr int QW = 16 * NQS;
    constexpr int QB = 2 * QW;
    constexpr int NKK = DH / 32;
    constexpr int NNT = DH / 16;
    constexpr int DG = DH / 8;          // 8-col groups per row
    constexpr int SLOTS = DG / 8;       // staging slots per thread
    constexpr int SZ_VT = 2 * NPAR * DH * KB * 2;
    constexpr int MST = DH + 4;
    constexpr int P = NPAR - 1;

    __shared__ __align__(16) char smem[SZ_VT];
    u16 (*Vt)[NPAR][DH][KB] = (u16 (*)[NPAR][DH][KB])smem;
    float* MrgAcc = (float*)smem;                         // [2*P][QW][MST]
    float* MrgML  = (float*)(smem + (size_t)2 * P * QW * MST * 4);

    const int nQT = L / QB;
    const int perAtt = 2 * NHEADS * nQT;
    const int att = blockIdx.x / perAtt;
    const int rem = blockIdx.x - att * perAtt;
    const int qt = rem % nQT;
    const int bh = rem / nQT;
    const u16* __restrict__ Q = att ? Q2 : Q1;
    const u16* __restrict__ K = att ? K2 : K1;
    const u16* __restrict__ V = att ? V2 : V1;
    u16* __restrict__ O = att ? O2 : O1;

    const int tid = threadIdx.x;
    const int w = tid >> 6;
    const int lane = tid & 63;
    const int lo = lane & 15, hi = lane >> 4;
    const int qg = w & 1, par = w >> 1;
    const int q0 = qt * QB + qg * QW;

    short8 qf[NQS][NKK];
    #pragma unroll
    for (int qs = 0; qs < NQS; ++qs)
        #pragma unroll
        for (int kk = 0; kk < NKK; ++kk)
            qf[qs][kk] = *(const short8*)&Q[((size_t)bh * L + q0 + qs * 16 + lo) * DH + kk * 32 + hi * 8];

    f32x4 acc[NQS][NNT];
    #pragma unroll
    for (int qs = 0; qs < NQS; ++qs)
        #pragma unroll
        for (int nt = 0; nt < NNT; ++nt)
            #pragma unroll
            for (int r = 0; r < 4; ++r) acc[qs][nt][r] = 0.f;
    float m_i[NQS], l_i[NQS];
    #pragma unroll
    for (int qs = 0; qs < NQS; ++qs) { m_i[qs] = -1e30f; l_i[qs] = 0.f; }

    const u16* Kbase = K + (size_t)bh * S * DH;
    const u16* Vbase = V + (size_t)bh * S * DH;

    // K fragment registers, prefetched one round ahead (single buffer).
    short8 kf[4][NKK];
    auto load_kf = [&](int r) {
        const u16* Kt = Kbase + (size_t)(NPAR * r + par) * KB * DH;
        #pragma unroll
        for (int st = 0; st < 4; ++st)
            #pragma unroll
            for (int kk = 0; kk < NKK; ++kk)
                kf[st][kk] = *(const short8*)&Kt[(size_t)(st * 16 + lo) * DH + kk * 32 + hi * 8];
    };

    // V staging: thread stages tile-slot pt; SLOTS (s,d) units of 4 rows x 8 d
    const int pt = tid >> 7;
    const int u = tid & 127;
    int dV0[SLOTS], sV0[SLOTS];
    #pragma unroll
    for (int z = 0; z < SLOTS; ++z) {
        int e = u + z * 128;
        dV0[z] = (e % DG) * 8;
        sV0[z] = (e / DG) * 4;
    }

    u16x8 vreg[SLOTS][4];

    auto loadslots = [&](int r) {
        const u16* Vp = Vbase + (size_t)(NPAR * r + pt) * KB * DH;
        #pragma unroll
        for (int z = 0; z < SLOTS; ++z)
            #pragma unroll
            for (int si = 0; si < 4; ++si)
                vreg[z][si] = *(const u16x8*)&Vp[(size_t)(sV0[z] + si) * DH + dV0[z]];
    };
    auto writeslots = [&](int buf) {
        #pragma unroll
        for (int z = 0; z < SLOTS; ++z)
            #pragma unroll
            for (int j = 0; j < 8; ++j) {
                int d = dV0[z] + j;
                int g = ((d >> 3) ^ d) & 7;
                int scol = (sV0[z] & 7) | ((((sV0[z] >> 3) ^ g) & 7) << 3);
                u16x4 wj = {vreg[z][0][j], vreg[z][1][j], vreg[z][2][j], vreg[z][3][j]};
                *(u16x4*)&Vt[buf][pt][d][scol] = wj;
            }
    };

    const int NR = S / (KB * NPAR);

    load_kf(0);
    loadslots(0);
    writeslots(0);
    __syncthreads();
    if (1 < NR) loadslots(1);

    for (int r = 0; r < NR; ++r) {
        const int cur = r & 1;

        // ---- QK^T (swapped) from prefetched kf registers
        f32x4 sacc[4][NQS];
        #pragma unroll
        for (int st = 0; st < 4; ++st)
            #pragma unroll
            for (int qs = 0; qs < NQS; ++qs)
                #pragma unroll
                for (int rr = 0; rr < 4; ++rr) sacc[st][qs][rr] = 0.f;
        #pragma unroll
        for (int st = 0; st < 4; ++st) {
            #pragma unroll
            for (int kk = 0; kk < NKK; ++kk) {
                #pragma unroll
                for (int qs = 0; qs < NQS; ++qs)
                    sacc[st][qs] = __builtin_amdgcn_mfma_f32_16x16x32_bf16(
                        kf[st][kk], qf[qs][kk], sacc[st][qs], 0, 0, 0);
            }
        }

        // ---- prefetch next round's K fragments (hidden under softmax+PV)
        if (r + 1 < NR) load_kf(r + 1);

        // ---- softmax prologue: row max, defer-max, acc rescale
        float mn[NQS], ts[NQS];
        #pragma unroll
        for (int qs = 0; qs < NQS; ++qs) {
            float tm = -1e30f;
            #pragma unroll
            for (int st = 0; st < 4; ++st)
                #pragma unroll
                for (int rr = 0; rr < 4; ++rr) tm = fmaxf(tm, sacc[st][qs][rr]);
            tm = fmaxf(tm, __shfl_xor(tm, 16));
            tm = fmaxf(tm, __shfl_xor(tm, 32));
            const bool grow = __any(tm > m_i[qs] + 8.0f);
            mn[qs] = grow ? fmaxf(m_i[qs], tm) : m_i[qs];
            ts[qs] = 0.f;
            if (grow) {
                float alpha = __builtin_amdgcn_exp2f(m_i[qs] - mn[qs]);
                m_i[qs] = mn[qs];
                l_i[qs] *= alpha;
                float ar[4];
                #pragma unroll
                for (int rr = 0; rr < 4; ++rr) ar[rr] = __shfl(alpha, hi * 4 + rr);
                #pragma unroll
                for (int nt = 0; nt < NNT; ++nt)
                    #pragma unroll
                    for (int rr = 0; rr < 4; ++rr) acc[qs][nt][rr] *= ar[rr];
            }
        }

        // ---- stage round r+1's V into the other buffer (overlaps PV)
        if (r + 1 < NR) writeslots(cur ^ 1);

        // ---- fused exp + PV per 16-col strip, Vt[cur]
        __builtin_amdgcn_s_setprio(1);
        #pragma unroll
        for (int st = 0; st < 4; ++st) {
            short4v pa_[NQS];
            #pragma unroll
            for (int qs = 0; qs < NQS; ++qs) {
                float p0 = __builtin_amdgcn_exp2f(sacc[st][qs][0] - mn[qs]);
                float p1 = __builtin_amdgcn_exp2f(sacc[st][qs][1] - mn[qs]);
                float p2 = __builtin_amdgcn_exp2f(sacc[st][qs][2] - mn[qs]);
                float p3 = __builtin_amdgcn_exp2f(sacc[st][qs][3] - mn[qs]);
                ts[qs] += (p0 + p1) + (p2 + p3);
                short4v pk = {(short)f2bf(p0), (short)f2bf(p1),
                              (short)f2bf(p2), (short)f2bf(p3)};
                pa_[qs] = pk;
            }
            const int s0 = st * 16 + hi * 4;
            #pragma unroll
            for (int nt = 0; nt < NNT; ++nt) {
                int d = nt * 16 + lo;
                int g = ((d >> 3) ^ d) & 7;
                int scol = (s0 & 7) | ((((s0 >> 3) ^ g) & 7) << 3);
                short4v vb = *(const short4v*)&Vt[cur][par][d][scol];
                #pragma unroll
                for (int qs = 0; qs < NQS; ++qs)
                    acc[qs][nt] = __builtin_amdgcn_mfma_f32_16x16x16bf16_1k(
                        pa_[qs], vb, acc[qs][nt], 0, 0, 0);
            }
        }
        __builtin_amdgcn_s_setprio(0);

        // ---- finalize l
        #pragma unroll
        for (int qs = 0; qs < NQS; ++qs) {
            float t2 = ts[qs];
            t2 += __shfl_xor(t2, 16);
            t2 += __shfl_xor(t2, 32);
            l_i[qs] += t2;
        }

        __syncthreads();
        if (r + 2 < NR) loadslots(r + 2);
    }

    // ---- NPAR-way merge epilogue (MrgAcc/MrgML alias the Vt region)
    const int b_ = bh / NHEADS, h_ = bh % NHEADS;
    if (par != 0) {
        const int mi = qg * P + par - 1;
        float* ma = MrgAcc + (size_t)mi * QW * MST;
        #pragma unroll
        for (int qs = 0; qs < NQS; ++qs) {
            #pragma unroll
            for (int nt = 0; nt < NNT; ++nt)
                #pragma unroll
                for (int rr = 0; rr < 4; ++rr)
                    ma[(size_t)(qs * 16 + hi * 4 + rr) * MST + nt * 16 + lo] = acc[qs][nt][rr];
            if (hi == 0) {
                MrgML[(mi * 2 + 0) * QW + qs * 16 + lo] = m_i[qs];
                MrgML[(mi * 2 + 1) * QW + qs * 16 + lo] = l_i[qs];
            }
        }
    }
    __syncthreads();
    if (par == 0) {
        #pragma unroll
        for (int qs = 0; qs < NQS; ++qs) {
            float mp[P > 0 ? P : 1], lp[P > 0 ? P : 1];
            float mt = m_i[qs];
            #pragma unroll
            for (int p = 0; p < P; ++p) {
                mp[p] = MrgML[((qg * P + p) * 2 + 0) * QW + qs * 16 + lo];
                lp[p] = MrgML[((qg * P + p) * 2 + 1) * QW + qs * 16 + lo];
                mt = fmaxf(mt, mp[p]);
            }
            float c0 = __builtin_amdgcn_exp2f(m_i[qs] - mt);
            float lt = c0 * l_i[qs];
            float cp[P > 0 ? P : 1];
            #pragma unroll
            for (int p = 0; p < P; ++p) {
                cp[p] = __builtin_amdgcn_exp2f(mp[p] - mt);
                lt += cp[p] * lp[p];
            }
            float linv = 1.0f / lt;
            c0 *= linv;
            #pragma unroll
            for (int p = 0; p < P; ++p) cp[p] *= linv;
            float c0r[4], cpr[P > 0 ? P : 1][4];
            #pragma unroll
            for (int rr = 0; rr < 4; ++rr) {
                c0r[rr] = __shfl(c0, hi * 4 + rr);
                #pragma unroll
                for (int p = 0; p < P; ++p) cpr[p][rr] = __shfl(cp[p], hi * 4 + rr);
            }
            #pragma unroll
            for (int nt = 0; nt < NNT; ++nt)
                #pragma unroll
                for (int rr = 0; rr < 4; ++rr) {
                    int q = qs * 16 + hi * 4 + rr;
                    float ov = acc[qs][nt][rr] * c0r[rr];
                    #pragma unroll
                    for (int p = 0; p < P; ++p)
                        ov += MrgAcc[((size_t)(qg * P + p) * QW + q) * MST + nt * 16 + lo] * cpr[p][rr];
                    O[(((size_t)b_ * L + q0 + q) * NHEADS + h_) * DH + nt * 16 + lo] = f2bf(ov);
                }
        }
    }
}

// ---------------------------------------------------------------------------
// Level-3 flash: 128 threads, 2 waves, in-reg P.
// ---------------------------------------------------------------------------
template <int DH, int NQS, int PRE>
__global__ __launch_bounds__(128) void flash_mfma(
    const u16* __restrict__ Q1, const u16* __restrict__ K1,
    const u16* __restrict__ V1, u16* __restrict__ O1,
    const u16* __restrict__ Q2, const u16* __restrict__ K2,
    const u16* __restrict__ V2, u16* __restrict__ O2, int L, int S)
{
    constexpr int KB = 64;
    constexpr int QW = NQS * 16;
    constexpr int QB = 2 * QW;
    constexpr int DH8 = DH / 8;
    constexpr int KC = (KB * DH8) / 128;
    constexpr int VU = (16 * DH8) / 128;
    constexpr int NKK = DH / 32;
    constexpr int NNT = DH / 16;

    __shared__ __align__(16) u16 Ks[KB][DH + 8];
    __shared__ __align__(16) u16 Vt[DH][KB];

    const int nQT = L / QB;
    const int perAtt = 2 * NHEADS * nQT;
    const int att = blockIdx.x / perAtt;
    const int rem = blockIdx.x - att * perAtt;
    const int qt = rem % nQT;
    const int bh = rem / nQT;
    const u16* __restrict__ Q = att ? Q2 : Q1;
    const u16* __restrict__ K = att ? K2 : K1;
    const u16* __restrict__ V = att ? V2 : V1;
    u16* __restrict__ O = att ? O2 : O1;

    const int tid = threadIdx.x;
    const int wv = tid >> 6;
    const int lane = tid & 63;
    const int lo = lane & 15;
    const int hi = lane >> 4;
    const int q0 = qt * QB + wv * QW;

    short8 qf[NQS][NKK];
    #pragma unroll
    for (int qs = 0; qs < NQS; ++qs)
        #pragma unroll
        for (int kk = 0; kk < NKK; ++kk)
            qf[qs][kk] = *(const short8*)&Q[((size_t)bh * L + q0 + qs * 16 + lo) * DH + kk * 32 + hi * 8];

    f32x4 acc[NQS][NNT];
    #pragma unroll
    for (int qs = 0; qs < NQS; ++qs)
        #pragma unroll
        for (int nt = 0; nt < NNT; ++nt)
            #pragma unroll
            for (int r = 0; r < 4; ++r) acc[qs][nt][r] = 0.f;
    float m_i[NQS], l_i[NQS];
    #pragma unroll
    for (int qs = 0; qs < NQS; ++qs) { m_i[qs] = -1e30f; l_i[qs] = 0.f; }

    const int NT = S / KB;
    u16x8 kreg[PRE ? KC : 1];
    u16x8 vreg[PRE ? VU : 1][4];

    const u16* Kbase = K + (size_t)bh * S * DH;
    const u16* Vbase = V + (size_t)bh * S * DH;

    auto vwrite = [&](int d, int s0, u16x4 wj) {
        int g = ((d >> 3) ^ d) & 7;
        int scol = (s0 & 7) | ((((s0 >> 3) ^ g) & 7) << 3);
        *(u16x4*)&Vt[d][scol] = wj;
    };

    if (PRE) {
        #pragma unroll
        for (int i = 0; i < KC; ++i) {
            int idx = tid + i * 128;
            kreg[i] = *(const u16x8*)&Kbase[(size_t)(idx / DH8) * DH + (idx % DH8) * 8];
        }
        #pragma unroll
        for (int u = 0; u < VU; ++u) {
            int uu = tid + u * 128;
            int d0 = (uu % DH8) * 8, s0 = (uu / DH8) * 4;
            #pragma unroll
            for (int si = 0; si < 4; ++si)
                vreg[u][si] = *(const u16x8*)&Vbase[(size_t)(s0 + si) * DH + d0];
        }
    }

    for (int t = 0; t < NT; ++t) {
        __syncthreads();
        if (PRE) {
            #pragma unroll
            for (int i = 0; i < KC; ++i) {
                int idx = tid + i * 128;
                *(u16x8*)&Ks[idx / DH8][(idx % DH8) * 8] = kreg[i];
            }
            #pragma unroll
            for (int u = 0; u < VU; ++u) {
                int uu = tid + u * 128;
                int d0 = (uu % DH8) * 8, s0 = (uu / DH8) * 4;
                #pragma unroll
                for (int j = 0; j < 8; ++j) {
                    u16x4 wj = {vreg[u][0][j], vreg[u][1][j], vreg[u][2][j], vreg[u][3][j]};
                    vwrite(d0 + j, s0, wj);
                }
            }
        } else {
            const u16* Kp = Kbase + (size_t)t * KB * DH;
            const u16* Vp = Vbase + (size_t)t * KB * DH;
            #pragma unroll
            for (int i = 0; i < KC; ++i) {
                int idx = tid + i * 128;
                *(u16x8*)&Ks[idx / DH8][(idx % DH8) * 8] =
                    *(const u16x8*)&Kp[(size_t)(idx / DH8) * DH + (idx % DH8) * 8];
            }
            #pragma unroll
            for (int u = 0; u < VU; ++u) {
                int uu = tid + u * 128;
                int d0 = (uu % DH8) * 8, s0 = (uu / DH8) * 4;
                u16x8 v0 = *(const u16x8*)&Vp[(size_t)(s0 + 0) * DH + d0];
                u16x8 v1 = *(const u16x8*)&Vp[(size_t)(s0 + 1) * DH + d0];
                u16x8 v2 = *(const u16x8*)&Vp[(size_t)(s0 + 2) * DH + d0];
                u16x8 v3 = *(const u16x8*)&Vp[(size_t)(s0 + 3) * DH + d0];
                #pragma unroll
                for (int j = 0; j < 8; ++j) {
                    u16x4 wj = {v0[j], v1[j], v2[j], v3[j]};
                    vwrite(d0 + j, s0, wj);
                }
            }
        }
        __syncthreads();

        if (PRE && t + 1 < NT) {
            const u16* Kp = Kbase + (size_t)(t + 1) * KB * DH;
            const u16* Vp = Vbase + (size_t)(t + 1) * KB * DH;
            #pragma unroll
            for (int i = 0; i < KC; ++i) {
                int idx = tid + i * 128;
                kreg[i] = *(const u16x8*)&Kp[(size_t)(idx / DH8) * DH + (idx % DH8) * 8];
            }
            #pragma unroll
            for (int u = 0; u < VU; ++u) {
                int uu = tid + u * 128;
                int d0 = (uu % DH8) * 8, s0 = (uu / DH8) * 4;
                #pragma unroll
                for (int si = 0; si < 4; ++si)
                    vreg[u][si] = *(const u16x8*)&Vp[(size_t)(s0 + si) * DH + d0];
            }
        }

        f32x4 sacc[4][NQS];
        #pragma unroll
        for (int st = 0; st < 4; ++st)
            #pragma unroll
            for (int qs = 0; qs < NQS; ++qs)
                #pragma unroll
                for (int r = 0; r < 4; ++r) sacc[st][qs][r] = 0.f;
        #pragma unroll
        for (int st = 0; st < 4; ++st) {
            #pragma unroll
            for (int kk = 0; kk < NKK; ++kk) {
                short8 a = *(const short8*)&Ks[st * 16 + lo][kk * 32 + hi * 8];
                #pragma unroll
                for (int qs = 0; qs < NQS; ++qs)
                    sacc[st][qs] = __builtin_amdgcn_mfma_f32_16x16x32_bf16(
                        a, qf[qs][kk], sacc[st][qs], 0, 0, 0);
            }
        }

        float mn[NQS], ts[NQS];
        #pragma unroll
        for (int qs = 0; qs < NQS; ++qs) {
            float tm = -1e30f;
            #pragma unroll
            for (int st = 0; st < 4; ++st)
                #pragma unroll
                for (int r = 0; r < 4; ++r) tm = fmaxf(tm, sacc[st][qs][r]);
            tm = fmaxf(tm, __shfl_xor(tm, 16));
            tm = fmaxf(tm, __shfl_xor(tm, 32));
            const bool grow = __any(tm > m_i[qs] + 8.0f);
            mn[qs] = grow ? fmaxf(m_i[qs], tm) : m_i[qs];
            ts[qs] = 0.f;
            if (grow) {
                float alpha = __builtin_amdgcn_exp2f(m_i[qs] - mn[qs]);
                m_i[qs] = mn[qs];
                l_i[qs] *= alpha;
                float ar[4];
                #pragma unroll
                for (int r = 0; r < 4; ++r) ar[r] = __shfl(alpha, hi * 4 + r);
                #pragma unroll
                for (int nt = 0; nt < NNT; ++nt)
                    #pragma unroll
                    for (int r = 0; r < 4; ++r) acc[qs][nt][r] *= ar[r];
            }
        }

        #pragma unroll
        for (int st = 0; st < 4; ++st) {
            short4v pa_[NQS];
            #pragma unroll
            for (int qs = 0; qs < NQS; ++qs) {
                float p0 = __builtin_amdgcn_exp2f(sacc[st][qs][0] - mn[qs]);
                float p1 = __builtin_amdgcn_exp2f(sacc[st][qs][1] - mn[qs]);
                float p2 = __builtin_amdgcn_exp2f(sacc[st][qs][2] - mn[qs]);
                float p3 = __builtin_amdgcn_exp2f(sacc[st][qs][3] - mn[qs]);
                ts[qs] += (p0 + p1) + (p2 + p3);
                short4v pk = {(short)f2bf(p0), (short)f2bf(p1),
                              (short)f2bf(p2), (short)f2bf(p3)};
                pa_[qs] = pk;
            }
            const int s0 = st * 16 + hi * 4;
            #pragma unroll
            for (int nt = 0; nt < NNT; ++nt) {
                int d = nt * 16 + lo;
                int g = ((d >> 3) ^ d) & 7;
                int scol = (s0 & 7) | ((((s0 >> 3) ^ g) & 7) << 3);
                short4v vb = *(const short4v*)&Vt[d][scol];
                #pragma unroll
                for (int qs = 0; qs < NQS; ++qs)
                    acc[qs][nt] = __builtin_amdgcn_mfma_f32_16x16x16bf16_1k(
                        pa_[qs], vb, acc[qs][nt], 0, 0, 0);
            }
        }

        #pragma unroll
        for (int qs = 0; qs < NQS; ++qs) {
            float t2 = ts[qs];
            t2 += __shfl_xor(t2, 16);
            t2 += __shfl_xor(t2, 32);
            l_i[qs] += t2;
        }
    }

    const int b_ = bh / NHEADS, h_ = bh % NHEADS;
    #pragma unroll
    for (int qs = 0; qs < NQS; ++qs) {
        float inv = 1.0f / l_i[qs];
        float ir[4];
        #pragma unroll
        for (int r = 0; r < 4; ++r) ir[r] = __shfl(inv, hi * 4 + r);
        #pragma unroll
        for (int nt = 0; nt < NNT; ++nt)
            #pragma unroll
            for (int r = 0; r < 4; ++r) {
                int l = q0 + qs * 16 + hi * 4 + r;
                O[(((size_t)b_ * L + l) * NHEADS + h_) * DH + nt * 16 + lo] =
                    f2bf(acc[qs][nt][r] * ir[r]);
            }
    }
}

// ---------------------------------------------------------------------------

extern "C" void kernel_launch(void* const* d_in, const int* in_sizes, int n_in,
                              void* d_out, int out_size, void* d_ws, size_t ws_size,
                              hipStream_t stream)
{
    static const int CHs[4] = {64, 128, 256, 512};
    static const int HWs[4] = {128, 64, 32, 16};

    const float* f1[4] = {(const float*)d_in[0], (const float*)d_in[1],
                          (const float*)d_in[2], (const float*)d_in[3]};
    const float* f2[4] = {nullptr, (const float*)d_in[4], (const float*)d_in[6],
                          (const float*)d_in[8]};
    const float* f3[4] = {nullptr, (const float*)d_in[5], (const float*)d_in[7],
                          (const float*)d_in[9]};

    // level 0: pass-through
    size_t out0_elems = (size_t)in_sizes[0];
    hipMemcpyAsync(d_out, d_in[0], out0_elems * sizeof(float),
                   hipMemcpyDeviceToDevice, stream);

    // workspace: 11 slots of 2*4096*128 u16 (22 MB), reused per level.
    const size_t SL = (size_t)2 * 4096 * 128;
    u16* wsu = (u16*)d_ws;
    u16* f1t = wsu + 0 * SL;
    u16* f2t = wsu + 1 * SL;   // aliases Ana after qkv
    u16* f3t = wsu + 2 * SL;   // aliases Anb after qkv
    u16* Qa  = wsu + 3 * SL;
    u16* Ka  = wsu + 4 * SL;
    u16* Va  = wsu + 5 * SL;
    u16* Qb  = wsu + 6 * SL;
    u16* Kb  = wsu + 7 * SL;
    u16* Vb  = wsu + 8 * SL;
    u16* A1t = wsu + 9 * SL;
    u16* A2t = wsu + 10 * SL;
    u16* Ana = f2t;
    u16* Anb = f3t;

    const float LOG2E = 1.44269504088896340736f;

    size_t outOff = out0_elems;
    for (int lvl = 1; lvl <= 3; ++lvl) {
        const int C = CHs[lvl];
        const int Hs = HWs[lvl];
        const int L = Hs * Hs;
        const int dh = C / NHEADS;
        const int M = 2 * L;  // B*L
        const float qscale = LOG2E / sqrtf((float)dh);
        const int bi = 10 + (lvl - 1) * 10;
        const float* a12w  = (const float*)d_in[bi + 0];
        const float* a12b  = (const float*)d_in[bi + 1];
        const float* a12ow = (const float*)d_in[bi + 2];
        const float* a12ob = (const float*)d_in[bi + 3];
        const float* a13w  = (const float*)d_in[bi + 4];
        const float* a13b  = (const float*)d_in[bi + 5];
        const float* a13ow = (const float*)d_in[bi + 6];
        const float* a13ob = (const float*)d_in[bi + 7];
        const float* sqw   = (const float*)d_in[bi + 8];
        const float* sqb   = (const float*)d_in[bi + 9];

        // 1) transpose f1/f2/f3 -> bf16 [b, l, c]
        dim3 tg(L / 32, C / 32, 6);
        transpose_bf16_kernel<<<tg, 256, 0, stream>>>(f1[lvl], f2[lvl], f3[lvl],
                                                      f1t, f2t, f3t, C, L);

        // 2) fused qkv (both attentions)
        const int gx = 3 * C / 64;
        const int perAtt = gx * (M / 64);
        gemm_qkv<<<2 * perAtt, 256, 0, stream>>>(
            f1t, f2t, f3t, a12w, a12b, a13w, a13b,
            Qa, Ka, Va, Qb, Kb, Vb, M, C, L, dh, qscale, gx, perAtt);

        // 3) fused flash (both attentions)
        if (dh == 64)
            flash_split<64, 4, 2><<<2 * (2 * NHEADS) * (L / 64), 512, 0, stream>>>(
                Qa, Ka, Va, Ana, Qb, Kb, Vb, Anb, L, L);
        else if (dh == 128)
            flash_split<128, 2, 1><<<2 * (2 * NHEADS) * (L / 32), 256, 0, stream>>>(
                Qa, Ka, Va, Ana, Qb, Kb, Vb, Anb, L, L);
        else
            flash_mfma<256, 1, 0><<<2 * (2 * NHEADS) * (L / 32), 128, 0, stream>>>(
                Qa, Ka, Va, Ana, Qb, Kb, Vb, Anb, L, L);

        // 4) fused out_proj (both attentions)
        const int gx2 = C / 64;
        const int perAtt2 = gx2 * (M / 64);
        gemm_proj<<<2 * perAtt2, 256, 0, stream>>>(
            Ana, Anb, a12ow, a12ob, a13ow, a13ob, A1t, A2t, M, C, gx2, perAtt2);

        // 5) squeeze into d_out (fp32 [b, n, l])
        dim3 gsq(C / 64, M / 64);
        gemm_squeeze<<<gsq, 256, 0, stream>>>(f1t, A1t, A2t, sqw, sqb,
                                              (float*)d_out + outOff, M, C, L);
        outOff += (size_t)2 * C * L;
    }
}